// Round 7
// baseline (8453.292 us; speedup 1.0000x reference)
//
#include <hip/hip_runtime.h>
#include <hip/hip_bf16.h>
#include <math.h>

// Problem constants
#define NB 8
#define NIN 256
#define NHID 256
#define NMEM 64
#define NSEQ 2048
#define NFEAT 64
#define NOUTCH 320        // NFEAT + NHID
#define NFFT 4096
#define KBINS 2049        // NSEQ + 1
#define CHUNK 256
#define NCHUNK 9          // ceil(2049/256)

// ws layout (float offsets) — TOTAL ~14.4 MB (OOB-hardened: fits any
// plausible ws_size; round-6 48MB layout is the suspected OOB cause)
#define FFTU_OFF 0
#define FFTU_SZ (NB * NFEAT * KBINS * 2)               // 2,098,176 (8.4 MB)
#define UZ_OFF (FFTU_OFF + FFTU_SZ)                    // ubuf / Zchunk overlay
#define UZ_SZ (NB * NFEAT * NSEQ)                      // 1,048,576 (4.2 MB)
                                                       // Zchunk needs NB*NHID*CHUNK*2 = same
#define FHD_OFF (UZ_OFF + UZ_SZ)
#define FHD_SZ (NMEM * KBINS * 2)                      // 262,272 (1.05 MB)
#define TW4_OFF (FHD_OFF + FHD_SZ)
#define TW4_SZ (4096 * 2)                              // 32 KB
#define HBUF_OFF (TW4_OFF + TW4_SZ)
#define HBUF_SZ (NMEM * NSEQ)                          // 131,072 (0.52 MB)
#define D64_OFF ((HBUF_OFF + HBUF_SZ + 1) & ~1)        // 8B-aligned
// f64 scratch: M(4225) E(4225) T(4225) Tn(4225) Ad(4096) Bd(64) = 21060 dbl
// end = D64_OFF + 42120 floats = 3,590,408 floats = 14.36 MB

// ---------------------------------------------------------------------------
// k0: tw4[m] = exp(-2*pi*i*m/4096), m in [0,4096), double precision.
// ---------------------------------------------------------------------------
__global__ void k0_tw4(float2* __restrict__ tw4) {
  int m = blockIdx.x * 256 + threadIdx.x;
  if (m < 4096) {
    double ang = -2.0 * 3.14159265358979323846 * (double)m / 4096.0;
    tw4[m] = make_float2((float)cos(ang), (float)sin(ang));
  }
}

// ---------------------------------------------------------------------------
// kA: replicate reference _lmu_fft_kernel discretization in fp64.
// blk = [[A,B],[0,0]] (65x65); scaling-squaring Taylor expm (29 terms,
// s = ceil(log2(norm1))+1); emit Ad (64x64), Bd (64) rounded through f32.
// ---------------------------------------------------------------------------
__global__ __launch_bounds__(256) void kA_expm(double* __restrict__ D) {
  double* M  = D;          // 65x65
  double* E  = D + 4225;
  double* T  = D + 8450;
  double* Tn = D + 12675;
  double* Ad = D + 16900;  // 64x64
  double* Bd = D + 20996;  // 64
  const int tid = threadIdx.x;
  __shared__ double sh_scale;
  __shared__ int sh_s;
  for (int e = tid; e < 4225; e += 256) {
    int i = e / 65, j = e % 65;
    double val = 0.0;
    if (i < 64) {
      double R = (2.0 * i + 1.0) / 2048.0;
      if (j < 64) val = R * ((i < j) ? -1.0 : (((i - j) & 1) ? 1.0 : -1.0));
      else        val = R * ((i & 1) ? -1.0 : 1.0);   // Bc = R*(-1)^i
    }
    M[e] = val;
  }
  __syncthreads();
  if (tid == 0) {
    double norm = 0.0;
    for (int j = 0; j < 65; ++j) {
      double cs = 0.0;
      for (int i = 0; i < 65; ++i) cs += fabs(M[i * 65 + j]);
      if (cs > norm) norm = cs;
    }
    if (norm < 1e-16) norm = 1e-16;
    int s = (int)ceil(log2(norm)) + 1;
    if (s < 0) s = 0;
    sh_s = s;
    double sc = 1.0;
    for (int q = 0; q < s; ++q) sc *= 0.5;
    sh_scale = sc;
  }
  __syncthreads();
  const double scale = sh_scale;
  const int s = sh_s;
  for (int e = tid; e < 4225; e += 256) {
    int i = e / 65, j = e % 65;
    M[e] *= scale;
    double id = (i == j) ? 1.0 : 0.0;
    E[e] = id; T[e] = id;
  }
  __syncthreads();
  for (int k = 1; k <= 29; ++k) {
    for (int e = tid; e < 4225; e += 256) {
      int i = e / 65, j = e % 65;
      double dot = 0.0;
      for (int l = 0; l < 65; ++l) dot += T[i * 65 + l] * M[l * 65 + j];
      Tn[e] = dot / (double)k;
    }
    __syncthreads();
    for (int e = tid; e < 4225; e += 256) { T[e] = Tn[e]; E[e] += Tn[e]; }
    __syncthreads();
  }
  for (int q = 0; q < s; ++q) {
    for (int e = tid; e < 4225; e += 256) {
      int i = e / 65, j = e % 65;
      double dot = 0.0;
      for (int l = 0; l < 65; ++l) dot += E[i * 65 + l] * E[l * 65 + j];
      Tn[e] = dot;
    }
    __syncthreads();
    for (int e = tid; e < 4225; e += 256) E[e] = Tn[e];
    __syncthreads();
  }
  for (int e = tid; e < 4096; e += 256)
    Ad[e] = (double)(float)E[(e >> 6) * 65 + (e & 63)];
  if (tid < 64) Bd[tid] = (double)(float)E[tid * 65 + 64];
}

// ---------------------------------------------------------------------------
// kB: impulse-response scan H[mi,t]: v_0 = Bd, v_{t+1} = Ad v_t (fp64).
// ---------------------------------------------------------------------------
__global__ __launch_bounds__(64) void kB_scan(const double* __restrict__ D,
                                              float* __restrict__ H) {
  const double* Ad = D + 16900;
  const double* Bd = D + 20996;
  __shared__ double Ads[64][64];
  __shared__ double v0[64], v1[64];
  const int i = threadIdx.x;
  for (int e = i; e < 4096; e += 64) Ads[e >> 6][e & 63] = Ad[e];
  v0[i] = Bd[i];
  __syncthreads();
  double* cur = v0; double* nxt = v1;
  for (int t = 0; t < NSEQ; ++t) {
    H[i * NSEQ + t] = (float)cur[i];
    double dot = 0.0;
#pragma unroll 16
    for (int j = 0; j < 64; ++j) dot += Ads[i][j] * cur[j];
    nxt[i] = dot;
    __syncthreads();
    double* tmp = cur; cur = nxt; nxt = tmp;
  }
}

// ---------------------------------------------------------------------------
// kC: fHd[mi,k] = rfft(H[mi,:], n=4096)[k]. Direct table DFT, 1 block/row.
// ---------------------------------------------------------------------------
__global__ __launch_bounds__(256) void kC_dft(const float* __restrict__ H,
                                              const float2* __restrict__ tw4,
                                              float* __restrict__ fHd) {
  __shared__ float HS[NSEQ];
  __shared__ float2 TWS[4096];
  const int tid = threadIdx.x;
  const int mi = blockIdx.x;
  for (int t = tid; t < NSEQ; t += 256) HS[t] = H[mi * NSEQ + t];
  for (int m = tid; m < 4096; m += 256) TWS[m] = tw4[m];
  __syncthreads();
  float2* dst = (float2*)fHd + (size_t)mi * KBINS;
  for (int k = tid; k < KBINS; k += 256) {
    float sr = 0.f, si = 0.f;
    int m = 0;
    for (int t = 0; t < NSEQ; ++t) {
      float2 w = TWS[m];
      float h = HS[t];
      sr = fmaf(h, w.x, sr);
      si = fmaf(h, w.y, si);
      m = (m + k) & 4095;
    }
    dst[k] = make_float2(sr, si);
  }
}

// ---------------------------------------------------------------------------
// k1n: out[b,o,s] = Wu_b[o] + sum_i Wu_w[o,i]*x[b,i,s]
//   o <  256 -> dout = acc + Wh_b[o]   (residual + final bias, chunks add)
//   o >= 256 -> ubuf = relu(acc)
// ---------------------------------------------------------------------------
__global__ __launch_bounds__(256) void k1n(
    const float* __restrict__ x, const float* __restrict__ Wuw,
    const float* __restrict__ Wub, const float* __restrict__ Whb,
    float* __restrict__ dout, float* __restrict__ ubuf) {
  int idx = blockIdx.x * 256 + threadIdx.x;
  int b = idx / (NOUTCH * NSEQ);
  int rem = idx % (NOUTCH * NSEQ);
  int o = rem >> 11;
  int s = rem & 2047;
  float acc = Wub[o];
  const float* xr = x + (size_t)b * NIN * NSEQ + s;
  const float* wr = Wuw + (size_t)o * NIN;
  for (int i = 0; i < NIN; ++i)
    acc = fmaf(wr[i], xr[(size_t)i * NSEQ], acc);
  if (o < NHID) {
    dout[((size_t)b * NHID + o) * NSEQ + s] = acc + Whb[o];
  } else {
    ubuf[((size_t)b * NFEAT + (o - NHID)) * NSEQ + s] = fmaxf(acc, 0.f);
  }
}

// ---------------------------------------------------------------------------
// k2n: direct rDFT: fft_u[b,f,k] = sum_t u[t] * e^{-2pi i k t / 4096}
// ---------------------------------------------------------------------------
__global__ __launch_bounds__(256) void k2n(
    const float* __restrict__ ubuf, const float2* __restrict__ tw4,
    float* __restrict__ fftu) {
  __shared__ float US[NSEQ];
  __shared__ float2 TWS[4096];
  const int tid = threadIdx.x;
  const int b = blockIdx.x >> 6, f = blockIdx.x & 63;
  const float* src = ubuf + ((size_t)b * NFEAT + f) * NSEQ;
  for (int t = tid; t < NSEQ; t += 256) US[t] = src[t];
  for (int m = tid; m < 4096; m += 256) TWS[m] = tw4[m];
  __syncthreads();
  float2* dst = (float2*)fftu + ((size_t)b * NFEAT + f) * KBINS;
  for (int k = tid; k < KBINS; k += 256) {
    float sr = 0.f, si = 0.f;
    int m = 0;
    for (int t = 0; t < NSEQ; ++t) {
      float2 w = TWS[m];
      float u = US[t];
      sr = fmaf(u, w.x, sr);
      si = fmaf(u, w.y, si);
      m = (m + k) & 4095;
    }
    dst[k] = make_float2(sr, si);
  }
}

// ---------------------------------------------------------------------------
// k3c: fused G+Z for one k-chunk [k0c, k0c+256).
//   G[o,f,k] = sum_mi Wh_w[o, f*64+mi] * fHd[mi,k]
//   Zc[b,o,kloc] = sum_f fft_u[b,f,k] * G[o,f,k]
// Block: 2 o's x 64 bins; grid (128, 4).
// ---------------------------------------------------------------------------
__global__ __launch_bounds__(256) void k3c(
    const float* __restrict__ Whw, const float* __restrict__ fHd,
    const float* __restrict__ fftu, float* __restrict__ Zc, int k0c) {
  __shared__ float2 WhP[4096];
  __shared__ float2 fHc[64][65];
  __shared__ float red[4][64][33];
  const int tid = threadIdx.x;
  const int o0 = blockIdx.x * 2;
  const int k0 = k0c + blockIdx.y * 64;

  for (int e = tid; e < 4096; e += 256)
    WhP[e] = make_float2(Whw[(size_t)o0 * 4096 + e],
                         Whw[(size_t)(o0 + 1) * 4096 + e]);
  for (int e = tid; e < 4096; e += 256) {
    int mi = e >> 6, kk = e & 63;
    int k = k0 + kk;
    float2 v = make_float2(0.f, 0.f);
    if (k < KBINS) v = ((const float2*)fHd)[(size_t)mi * KBINS + k];
    fHc[mi][kk] = v;
  }
  __syncthreads();

  const int tk = tid & 63, g = tid >> 6;
  const int k = k0 + tk;
  const bool kok = (k < KBINS);
  float zr[2][8], zi[2][8];
#pragma unroll
  for (int ol = 0; ol < 2; ++ol)
#pragma unroll
    for (int b = 0; b < 8; ++b) { zr[ol][b] = 0.f; zi[ol][b] = 0.f; }

  const float2* fu2 = (const float2*)fftu;
  for (int ff = 0; ff < 16; ++ff) {
    const int f = g * 16 + ff;
    float g0r = 0.f, g0i = 0.f, g1r = 0.f, g1i = 0.f;
#pragma unroll 16
    for (int mi = 0; mi < 64; ++mi) {
      float2 h = fHc[mi][tk];
      float2 w = WhP[f * 64 + mi];
      g0r = fmaf(w.x, h.x, g0r); g0i = fmaf(w.x, h.y, g0i);
      g1r = fmaf(w.y, h.x, g1r); g1i = fmaf(w.y, h.y, g1i);
    }
    if (kok) {
#pragma unroll
      for (int b = 0; b < 8; ++b) {
        float2 u = fu2[(size_t)(b * NFEAT + f) * KBINS + k];
        zr[0][b] = fmaf(u.x, g0r, fmaf(-u.y, g0i, zr[0][b]));
        zi[0][b] = fmaf(u.x, g0i, fmaf( u.y, g0r, zi[0][b]));
        zr[1][b] = fmaf(u.x, g1r, fmaf(-u.y, g1i, zr[1][b]));
        zi[1][b] = fmaf(u.x, g1i, fmaf( u.y, g1r, zi[1][b]));
      }
    }
  }
#pragma unroll
  for (int ol = 0; ol < 2; ++ol)
#pragma unroll
    for (int b = 0; b < 8; ++b) {
      red[g][tk][(ol * 8 + b) * 2 + 0] = zr[ol][b];
      red[g][tk][(ol * 8 + b) * 2 + 1] = zi[ol][b];
    }
  __syncthreads();
  if (g == 0 && kok) {
    float2* Z2 = (float2*)Zc;
    const int kloc = k - k0c;
#pragma unroll
    for (int ol = 0; ol < 2; ++ol)
#pragma unroll
      for (int b = 0; b < 8; ++b) {
        int i0 = (ol * 8 + b) * 2;
        float sr = red[0][tk][i0]     + red[1][tk][i0]
                 + red[2][tk][i0]     + red[3][tk][i0];
        float si = red[0][tk][i0 + 1] + red[1][tk][i0 + 1]
                 + red[2][tk][i0 + 1] + red[3][tk][i0 + 1];
        Z2[(size_t)(b * NHID + o0 + ol) * CHUNK + kloc] = make_float2(sr, si);
      }
  }
}

// ---------------------------------------------------------------------------
// k4c: accumulate this chunk's inverse-DFT contribution into dout:
//   dout[b,o,t] += (2/N) * sum_{kloc} c_k (Zr cos th - Zi sin th),
//   th = 2 pi k t / N, c_k = 0.5 at k=0 and k=2048 else 1 (folded into ZS).
// ---------------------------------------------------------------------------
__global__ __launch_bounds__(256) void k4c(
    const float* __restrict__ Zc, const float2* __restrict__ tw4,
    float* __restrict__ dout, int k0c) {
  __shared__ float2 ZS[CHUNK];
  __shared__ float2 TWS[4096];
  const int tid = threadIdx.x;
  const int b = blockIdx.x >> 8, o = blockIdx.x & 255;
  const int kmax = (KBINS - k0c < CHUNK) ? (KBINS - k0c) : CHUNK;
  const float2* Zrow = (const float2*)Zc + ((size_t)b * NHID + o) * CHUNK;
  if (tid < CHUNK) {
    float2 v = make_float2(0.f, 0.f);
    if (tid < kmax) {
      v = Zrow[tid];
      int k = k0c + tid;
      if (k == 0 || k == NSEQ) { v.x *= 0.5f; v.y *= 0.5f; }
    }
    ZS[tid] = v;
  }
  for (int m = tid; m < 4096; m += 256) TWS[m] = tw4[m];
  __syncthreads();
  const float inv2 = 2.0f / (float)NFFT;
  float* drow = dout + ((size_t)b * NHID + o) * NSEQ;
  for (int t = tid; t < NSEQ; t += 256) {
    float acc = 0.f;
    int m = (k0c * t) & 4095;
#pragma unroll 8
    for (int kloc = 0; kloc < CHUNK; ++kloc) {
      float2 w = TWS[m];
      float2 z = ZS[kloc];
      acc = fmaf(z.x, w.x, acc);
      acc = fmaf(z.y, w.y, acc);
      m = (m + t) & 4095;
    }
    drow[t] += acc * inv2;
  }
}

// ---------------------------------------------------------------------------
extern "C" void kernel_launch(void* const* d_in, const int* in_sizes, int n_in,
                              void* d_out, int out_size, void* d_ws, size_t ws_size,
                              hipStream_t stream) {
  const float* x   = (const float*)d_in[0];
  const float* Wuw = (const float*)d_in[1];
  const float* Wub = (const float*)d_in[2];
  const float* Whw = (const float*)d_in[3];
  const float* Whb = (const float*)d_in[4];
  // d_in[5] (fft_H) intentionally UNUSED: recomputed on-device in fp64.
  float* out = (float*)d_out;
  float* ws  = (float*)d_ws;

  float* fftu = ws + FFTU_OFF;
  float* uz   = ws + UZ_OFF;       // ubuf, later Zchunk (overlay)
  float* fHd  = ws + FHD_OFF;
  float2* tw4 = (float2*)(ws + TW4_OFF);
  float* Hbuf = ws + HBUF_OFF;
  double* D   = (double*)(ws + D64_OFF);

  k0_tw4<<<16, 256, 0, stream>>>(tw4);
  kA_expm<<<1, 256, 0, stream>>>(D);
  kB_scan<<<1, 64, 0, stream>>>(D, Hbuf);
  kC_dft<<<NMEM, 256, 0, stream>>>(Hbuf, tw4, fHd);
  k1n<<<(NB * NOUTCH * NSEQ) / 256, 256, 0, stream>>>(x, Wuw, Wub, Whb, out, uz);
  k2n<<<NB * NFEAT, 256, 0, stream>>>(uz, tw4, fftu);
  for (int c = 0; c < NCHUNK; ++c) {
    int k0c = c * CHUNK;
    k3c<<<dim3(NHID / 2, 4), 256, 0, stream>>>(Whw, fHd, fftu, uz, k0c);
    k4c<<<NB * NHID, 256, 0, stream>>>(uz, tw4, out, k0c);
  }
}

// Round 8
// 4862.437 us; speedup vs baseline: 1.7385x; 1.7385x over previous
//
#include <hip/hip_runtime.h>
#include <hip/hip_bf16.h>
#include <math.h>

// Problem constants
#define NB 8
#define NIN 256
#define NHID 256
#define NMEM 64
#define NSEQ 2048
#define NFEAT 64
#define NOUTCH 320        // NFEAT + NHID
#define NFFT 4096
#define KBINS 2049        // NSEQ + 1
#define OCH 32            // o-chunk size
#define NOCH 8            // 256 / 32

// ws layout (float offsets) — TOTAL 14.18 MB (within round-7 proven budget)
#define FFTU_OFF 0
#define FFTU_SZ (NB * NFEAT * KBINS * 2)               // 2,098,176 (8.4 MB)
#define UZ_OFF (FFTU_OFF + FFTU_SZ)                    // overlay: f64 scratch -> ubuf -> Z o-chunks
#define UZ_SZ (NB * OCH * KBINS * 2)                   // 1,049,088 (4.2 MB) >= ubuf 1,048,576
#define FHD_OFF (UZ_OFF + UZ_SZ)
#define FHD_SZ (NMEM * KBINS * 2)                      // 262,272 (1.05 MB)
#define TW_OFF (FHD_OFF + FHD_SZ)
#define TW_SZ (2048 * 2)                               // 16 KB
#define HBUF_OFF (TW_OFF + TW_SZ)
#define HBUF_SZ (NMEM * NSEQ)                          // 131,072 (0.52 MB)
// end = 3,544,704 floats = 14.18 MB

// f64 scratch layout (doubles, based at UZ_OFF; dead before ubuf is written)
#define DM_OFF   0        // 65x65
#define DE_OFF   4225
#define DT_OFF   8450
#define DTN_OFF  12675
#define DAD_OFF  16900    // 64x64
#define DBD_OFF  20996    // 64
#define DAD64_OFF 21060   // 64x64
#define DW_OFF   25156    // [64 r][64 j] = Ad^r Bd
#define DMK_OFF  29252    // [32 k][64][64] = (Ad^64)^k

// padded LDS index for FFT arrays (breaks power-of-2 stride bank conflicts)
#define FIDX(i) ((i) + ((i) >> 5) + ((i) >> 10))
#define FFT_LDS 4240

// ---------------------------------------------------------------------------
// shared 4096-pt radix-2 DIT core (data already bit-reversed into XR/XI)
// ---------------------------------------------------------------------------
__device__ __forceinline__ void fft4096_core(float* XR, float* XI,
                                             const float2* TWS, bool inverse) {
#pragma unroll 1
  for (int s = 1; s <= 12; ++s) {
    int half = 1 << (s - 1);
    int shift = 12 - s;
#pragma unroll
    for (int q = 0; q < 8; ++q) {
      int bf = threadIdx.x + q * 256;
      int j = bf & (half - 1);
      int base = ((bf >> (s - 1)) << s) + j;
      float2 w = TWS[j << shift];
      float wr = w.x, wi = inverse ? -w.y : w.y;
      int i0 = FIDX(base), i1 = FIDX(base + half);
      float ar = XR[i0], ai = XI[i0];
      float br = XR[i1], bi = XI[i1];
      float tr = wr * br - wi * bi, ti = wr * bi + wi * br;
      XR[i0] = ar + tr; XI[i0] = ai + ti;
      XR[i1] = ar - tr; XI[i1] = ai - ti;
    }
    __syncthreads();
  }
}

// ---------------------------------------------------------------------------
// k0: tw[m] = exp(-2*pi*i*m/4096), m in [0,2048), double precision.
// ---------------------------------------------------------------------------
__global__ void k0_tw(float2* __restrict__ tw) {
  int m = blockIdx.x * 256 + threadIdx.x;
  if (m < 2048) {
    double ang = -2.0 * 3.14159265358979323846 * (double)m / 4096.0;
    tw[m] = make_float2((float)cos(ang), (float)sin(ang));
  }
}

// ---------------------------------------------------------------------------
// kA: fp64 replicate of reference discretization + power tables.
//  1) blk=[[A,B],[0,0]] (65x65); Taylor expm (29 terms, s=2 squarings);
//     Ad,Bd rounded through f32 (as reference).
//  2) Ad64 = Ad^64 (6 squarings); W[r] = Ad^r Bd (r<64);
//     Mk[k] = (Ad64)^k (k<32)  ->  H[:,64k+r] = Mk[k] @ W[r] (kB).
// ---------------------------------------------------------------------------
__global__ __launch_bounds__(256) void kA_expm(double* __restrict__ D) {
  double* M    = D + DM_OFF;
  double* E    = D + DE_OFF;
  double* T    = D + DT_OFF;
  double* Tn   = D + DTN_OFF;
  double* Ad   = D + DAD_OFF;
  double* Bd   = D + DBD_OFF;
  double* Ad64 = D + DAD64_OFF;
  double* W    = D + DW_OFF;
  double* Mk   = D + DMK_OFF;
  const int tid = threadIdx.x;
  __shared__ double sh_scale;
  __shared__ int sh_s;
  for (int e = tid; e < 4225; e += 256) {
    int i = e / 65, j = e % 65;
    double val = 0.0;
    if (i < 64) {
      double R = (2.0 * i + 1.0) / 2048.0;
      if (j < 64) val = R * ((i < j) ? -1.0 : (((i - j) & 1) ? 1.0 : -1.0));
      else        val = R * ((i & 1) ? -1.0 : 1.0);   // Bc = R*(-1)^i
    }
    M[e] = val;
  }
  __syncthreads();
  if (tid == 0) {
    double norm = 0.0;
    for (int j = 0; j < 65; ++j) {
      double cs = 0.0;
      for (int i = 0; i < 65; ++i) cs += fabs(M[i * 65 + j]);
      if (cs > norm) norm = cs;
    }
    if (norm < 1e-16) norm = 1e-16;
    int s = (int)ceil(log2(norm)) + 1;
    if (s < 0) s = 0;
    sh_s = s;
    double sc = 1.0;
    for (int q = 0; q < s; ++q) sc *= 0.5;
    sh_scale = sc;
  }
  __syncthreads();
  const double scale = sh_scale;
  const int s = sh_s;
  for (int e = tid; e < 4225; e += 256) {
    int i = e / 65, j = e % 65;
    M[e] *= scale;
    double id = (i == j) ? 1.0 : 0.0;
    E[e] = id; T[e] = id;
  }
  __syncthreads();
  for (int k = 1; k <= 29; ++k) {
    for (int e = tid; e < 4225; e += 256) {
      int i = e / 65, j = e % 65;
      double dot = 0.0;
      for (int l = 0; l < 65; ++l) dot += T[i * 65 + l] * M[l * 65 + j];
      Tn[e] = dot / (double)k;
    }
    __syncthreads();
    for (int e = tid; e < 4225; e += 256) { T[e] = Tn[e]; E[e] += Tn[e]; }
    __syncthreads();
  }
  for (int q = 0; q < s; ++q) {
    for (int e = tid; e < 4225; e += 256) {
      int i = e / 65, j = e % 65;
      double dot = 0.0;
      for (int l = 0; l < 65; ++l) dot += E[i * 65 + l] * E[l * 65 + j];
      Tn[e] = dot;
    }
    __syncthreads();
    for (int e = tid; e < 4225; e += 256) E[e] = Tn[e];
    __syncthreads();
  }
  for (int e = tid; e < 4096; e += 256) {
    Ad[e] = (double)(float)E[(e >> 6) * 65 + (e & 63)];
    Ad64[e] = 0.0;  // init below
  }
  if (tid < 64) Bd[tid] = (double)(float)E[tid * 65 + 64];
  __syncthreads();
  // Ad64 = Ad^64 via 6 squarings
  for (int e = tid; e < 4096; e += 256) Ad64[e] = Ad[e];
  __syncthreads();
  for (int q = 0; q < 6; ++q) {
    for (int e = tid; e < 4096; e += 256) {
      int i = e >> 6, j = e & 63;
      double dot = 0.0;
      for (int l = 0; l < 64; ++l) dot += Ad64[i * 64 + l] * Ad64[l * 64 + j];
      Tn[e] = dot;
    }
    __syncthreads();
    for (int e = tid; e < 4096; e += 256) Ad64[e] = Tn[e];
    __syncthreads();
  }
  // W[r] = Ad^r Bd
  if (tid < 64) W[tid] = Bd[tid];
  __syncthreads();
  for (int r = 1; r < 64; ++r) {
    if (tid < 64) {
      double dot = 0.0;
      for (int j = 0; j < 64; ++j) dot += Ad[tid * 64 + j] * W[(r - 1) * 64 + j];
      W[r * 64 + tid] = dot;
    }
    __syncthreads();
  }
  // Mk[k] = (Ad64)^k
  for (int e = tid; e < 4096; e += 256)
    Mk[e] = ((e >> 6) == (e & 63)) ? 1.0 : 0.0;
  __syncthreads();
  for (int k = 1; k < 32; ++k) {
    for (int e = tid; e < 4096; e += 256) {
      int i = e >> 6, j = e & 63;
      double dot = 0.0;
      for (int l = 0; l < 64; ++l)
        dot += Mk[(k - 1) * 4096 + i * 64 + l] * Ad64[l * 64 + j];
      Tn[e] = dot;
    }
    __syncthreads();
    for (int e = tid; e < 4096; e += 256) Mk[k * 4096 + e] = Tn[e];
    __syncthreads();
  }
}

// ---------------------------------------------------------------------------
// kB: parallel impulse response. Block k (of 32): H[i, 64k+r] = Mk[k] @ W[r].
// ---------------------------------------------------------------------------
__global__ __launch_bounds__(256) void kB_cols(const double* __restrict__ D,
                                               float* __restrict__ H) {
  const double* W = D + DW_OFF;
  const double* Mrow = D + DMK_OFF + (size_t)blockIdx.x * 4096;
  __shared__ double Ms[4096];
  const int tid = threadIdx.x;
  for (int e = tid; e < 4096; e += 256) Ms[e] = Mrow[e];
  __syncthreads();
  const int c0 = blockIdx.x * 64;
  for (int e = tid; e < 4096; e += 256) {
    int i = e >> 6, r = e & 63;
    double dot = 0.0;
#pragma unroll 16
    for (int j = 0; j < 64; ++j) dot += Ms[i * 64 + j] * W[r * 64 + j];
    H[(size_t)i * NSEQ + c0 + r] = (float)dot;
  }
}

// ---------------------------------------------------------------------------
// kC: fHd[mi,k] = rfft(H[mi,:], n=4096)[k] via LDS FFT. 1 block/row.
// ---------------------------------------------------------------------------
__global__ __launch_bounds__(256) void kC_fft(const float* __restrict__ H,
                                              const float2* __restrict__ tw,
                                              float* __restrict__ fHd) {
  __shared__ float XR[FFT_LDS], XI[FFT_LDS];
  __shared__ float2 TWS[2048];
  const int tid = threadIdx.x;
  const int mi = blockIdx.x;
  const float* src = H + (size_t)mi * NSEQ;
  for (int i = tid; i < NFFT; i += 256) { XR[FIDX(i)] = 0.f; XI[FIDX(i)] = 0.f; }
  for (int i = tid; i < 2048; i += 256) TWS[i] = tw[i];
  __syncthreads();
  for (int i = tid; i < NSEQ; i += 256) {
    int r = __brev((unsigned)i) >> 20;
    XR[FIDX(r)] = src[i];
  }
  __syncthreads();
  fft4096_core(XR, XI, TWS, false);
  float2* dst = (float2*)fHd + (size_t)mi * KBINS;
  for (int k = tid; k < KBINS; k += 256)
    dst[k] = make_float2(XR[FIDX(k)], XI[FIDX(k)]);
}

// ---------------------------------------------------------------------------
// k1t: tiled GEMM out[b,o,s] = bias + sum_i Wu_w[o,i]*x[b,i,s]
//   o<256 -> dout = acc + Wu_b + Wh_b ; o>=256 -> ubuf = relu(acc + Wu_b)
// tile 64 o x 128 s, K-chunks 32; 256 thr; thread: 4 o x 8 s.
// ---------------------------------------------------------------------------
__global__ __launch_bounds__(256) void k1t(
    const float* __restrict__ x, const float* __restrict__ Wuw,
    const float* __restrict__ Wub, const float* __restrict__ Whb,
    float* __restrict__ dout, float* __restrict__ ubuf) {
  __shared__ float xs[32][128];
  __shared__ float wsh[32][68];
  const int tid = threadIdx.x;
  const int b = blockIdx.z;
  const int o0 = blockIdx.y * 64;
  const int s0 = blockIdx.x * 128;
  const int sx = tid & 15, oy = tid >> 4;
  float acc[4][8];
#pragma unroll
  for (int j = 0; j < 4; ++j)
#pragma unroll
    for (int l = 0; l < 8; ++l) acc[j][l] = 0.f;

  for (int i0 = 0; i0 < 256; i0 += 32) {
#pragma unroll
    for (int e4 = tid; e4 < 1024; e4 += 256) {
      int ii = e4 >> 5, ss4 = (e4 & 31) << 2;
      float4 v = *(const float4*)&x[(size_t)(b * NIN + i0 + ii) * NSEQ + s0 + ss4];
      *(float4*)&xs[ii][ss4] = v;
    }
#pragma unroll
    for (int e4 = tid; e4 < 512; e4 += 256) {
      int oj = e4 >> 3, ii4 = (e4 & 7) << 2;
      float4 v = *(const float4*)&Wuw[(o0 + oj) * NIN + i0 + ii4];
      wsh[ii4][oj] = v.x; wsh[ii4 + 1][oj] = v.y;
      wsh[ii4 + 2][oj] = v.z; wsh[ii4 + 3][oj] = v.w;
    }
    __syncthreads();
#pragma unroll 8
    for (int kk = 0; kk < 32; ++kk) {
      float4 a = *(const float4*)&wsh[kk][oy * 4];
      float4 b0 = *(const float4*)&xs[kk][sx * 4];
      float4 b1 = *(const float4*)&xs[kk][64 + sx * 4];
      float av[4] = {a.x, a.y, a.z, a.w};
      float bv[8] = {b0.x, b0.y, b0.z, b0.w, b1.x, b1.y, b1.z, b1.w};
#pragma unroll
      for (int j = 0; j < 4; ++j)
#pragma unroll
        for (int l = 0; l < 8; ++l) acc[j][l] = fmaf(av[j], bv[l], acc[j][l]);
    }
    __syncthreads();
  }
#pragma unroll
  for (int j = 0; j < 4; ++j) {
    int o = o0 + oy * 4 + j;
    if (o < NHID) {
      float bias = Wub[o] + Whb[o];
      size_t base = ((size_t)b * NHID + o) * NSEQ + s0;
      float4 v0 = make_float4(acc[j][0] + bias, acc[j][1] + bias,
                              acc[j][2] + bias, acc[j][3] + bias);
      float4 v1 = make_float4(acc[j][4] + bias, acc[j][5] + bias,
                              acc[j][6] + bias, acc[j][7] + bias);
      *(float4*)&dout[base + sx * 4] = v0;
      *(float4*)&dout[base + 64 + sx * 4] = v1;
    } else {
      float bias = Wub[o];
      size_t base = ((size_t)b * NFEAT + (o - NHID)) * NSEQ + s0;
      float4 v0 = make_float4(fmaxf(acc[j][0] + bias, 0.f), fmaxf(acc[j][1] + bias, 0.f),
                              fmaxf(acc[j][2] + bias, 0.f), fmaxf(acc[j][3] + bias, 0.f));
      float4 v1 = make_float4(fmaxf(acc[j][4] + bias, 0.f), fmaxf(acc[j][5] + bias, 0.f),
                              fmaxf(acc[j][6] + bias, 0.f), fmaxf(acc[j][7] + bias, 0.f));
      *(float4*)&ubuf[base + sx * 4] = v0;
      *(float4*)&ubuf[base + 64 + sx * 4] = v1;
    }
  }
}

// ---------------------------------------------------------------------------
// k2f: fft_u[b,f,k] = rfft(ubuf[b,f,:], n=4096)[k] via LDS FFT. 1 block/row.
// ---------------------------------------------------------------------------
__global__ __launch_bounds__(256) void k2f(
    const float* __restrict__ ubuf, const float2* __restrict__ tw,
    float* __restrict__ fftu) {
  __shared__ float XR[FFT_LDS], XI[FFT_LDS];
  __shared__ float2 TWS[2048];
  const int tid = threadIdx.x;
  const int b = blockIdx.x >> 6, f = blockIdx.x & 63;
  const float* src = ubuf + ((size_t)b * NFEAT + f) * NSEQ;
  for (int i = tid; i < NFFT; i += 256) { XR[FIDX(i)] = 0.f; XI[FIDX(i)] = 0.f; }
  for (int i = tid; i < 2048; i += 256) TWS[i] = tw[i];
  __syncthreads();
  for (int i = tid; i < NSEQ; i += 256) {
    int r = __brev((unsigned)i) >> 20;
    XR[FIDX(r)] = src[i];
  }
  __syncthreads();
  fft4096_core(XR, XI, TWS, false);
  float2* dst = (float2*)fftu + ((size_t)b * NFEAT + f) * KBINS;
  for (int k = tid; k < KBINS; k += 256)
    dst[k] = make_float2(XR[FIDX(k)], XI[FIDX(k)]);
}

// ---------------------------------------------------------------------------
// k3o: fused G+Z for one o-chunk (32 o's), all k.
//   G[o,f,k] = sum_mi Wh_w[o, f*64+mi] * fHd[mi,k]
//   Zc[b,olocal,k] = sum_f fft_u[b,f,k] * G[o,f,k]
// grid (16 o-pairs, 33 k-tiles of 64); block 256.
// ---------------------------------------------------------------------------
__global__ __launch_bounds__(256) void k3o(
    const float* __restrict__ Whw, const float* __restrict__ fHd,
    const float* __restrict__ fftu, float* __restrict__ Zc, int ob0) {
  __shared__ float2 WhP[4096];
  __shared__ float2 fHc[64][65];
  __shared__ float red[4][64][33];
  const int tid = threadIdx.x;
  const int ol0 = blockIdx.x * 2;          // o_local base (0..30)
  const int o0 = ob0 + ol0;
  const int k0 = blockIdx.y * 64;

  for (int e = tid; e < 4096; e += 256)
    WhP[e] = make_float2(Whw[(size_t)o0 * 4096 + e],
                         Whw[(size_t)(o0 + 1) * 4096 + e]);
  for (int e = tid; e < 4096; e += 256) {
    int mi = e >> 6, kk = e & 63;
    int k = k0 + kk;
    float2 v = make_float2(0.f, 0.f);
    if (k < KBINS) v = ((const float2*)fHd)[(size_t)mi * KBINS + k];
    fHc[mi][kk] = v;
  }
  __syncthreads();

  const int tk = tid & 63, g = tid >> 6;
  const int k = k0 + tk;
  const bool kok = (k < KBINS);
  float zr[2][8], zi[2][8];
#pragma unroll
  for (int ol = 0; ol < 2; ++ol)
#pragma unroll
    for (int b = 0; b < 8; ++b) { zr[ol][b] = 0.f; zi[ol][b] = 0.f; }

  const float2* fu2 = (const float2*)fftu;
  for (int ff = 0; ff < 16; ++ff) {
    const int f = g * 16 + ff;
    float g0r = 0.f, g0i = 0.f, g1r = 0.f, g1i = 0.f;
#pragma unroll 16
    for (int mi = 0; mi < 64; ++mi) {
      float2 h = fHc[mi][tk];
      float2 w = WhP[f * 64 + mi];
      g0r = fmaf(w.x, h.x, g0r); g0i = fmaf(w.x, h.y, g0i);
      g1r = fmaf(w.y, h.x, g1r); g1i = fmaf(w.y, h.y, g1i);
    }
    if (kok) {
#pragma unroll
      for (int b = 0; b < 8; ++b) {
        float2 u = fu2[(size_t)(b * NFEAT + f) * KBINS + k];
        zr[0][b] = fmaf(u.x, g0r, fmaf(-u.y, g0i, zr[0][b]));
        zi[0][b] = fmaf(u.x, g0i, fmaf( u.y, g0r, zi[0][b]));
        zr[1][b] = fmaf(u.x, g1r, fmaf(-u.y, g1i, zr[1][b]));
        zi[1][b] = fmaf(u.x, g1i, fmaf( u.y, g1r, zi[1][b]));
      }
    }
  }
#pragma unroll
  for (int ol = 0; ol < 2; ++ol)
#pragma unroll
    for (int b = 0; b < 8; ++b) {
      red[g][tk][(ol * 8 + b) * 2 + 0] = zr[ol][b];
      red[g][tk][(ol * 8 + b) * 2 + 1] = zi[ol][b];
    }
  __syncthreads();
  if (g == 0 && kok) {
    float2* Z2 = (float2*)Zc;
#pragma unroll
    for (int ol = 0; ol < 2; ++ol)
#pragma unroll
      for (int b = 0; b < 8; ++b) {
        int i0 = (ol * 8 + b) * 2;
        float sr = red[0][tk][i0]     + red[1][tk][i0]
                 + red[2][tk][i0]     + red[3][tk][i0];
        float si = red[0][tk][i0 + 1] + red[1][tk][i0 + 1]
                 + red[2][tk][i0 + 1] + red[3][tk][i0 + 1];
        Z2[((size_t)b * OCH + ol0 + ol) * KBINS + k] = make_float2(sr, si);
      }
  }
}

// ---------------------------------------------------------------------------
// k4f: irfft via LDS FFT; dout[b,o,t] += XR[t]/4096. 1 block per (b,olocal).
// ---------------------------------------------------------------------------
__global__ __launch_bounds__(256) void k4f(
    const float* __restrict__ Zc, const float2* __restrict__ tw,
    float* __restrict__ dout, int ob0) {
  __shared__ float XR[FFT_LDS], XI[FFT_LDS];
  __shared__ float2 TWS[2048];
  const int tid = threadIdx.x;
  const int b = blockIdx.x >> 5, ol = blockIdx.x & 31;
  const int o = ob0 + ol;
  const float2* Z2 = (const float2*)Zc + ((size_t)b * OCH + ol) * KBINS;
  for (int i = tid; i < 2048; i += 256) TWS[i] = tw[i];
  for (int i = tid; i < NFFT; i += 256) {
    float2 v;
    if (i < KBINS) v = Z2[i];
    else { v = Z2[NFFT - i]; v.y = -v.y; }
    int r = __brev((unsigned)i) >> 20;
    XR[FIDX(r)] = v.x; XI[FIDX(r)] = v.y;
  }
  __syncthreads();
  fft4096_core(XR, XI, TWS, true);
  const float inv = 1.0f / (float)NFFT;
  float* drow = dout + ((size_t)b * NHID + o) * NSEQ;
  for (int t = tid; t < NSEQ; t += 256)
    drow[t] += XR[FIDX(t)] * inv;
}

// ---------------------------------------------------------------------------
extern "C" void kernel_launch(void* const* d_in, const int* in_sizes, int n_in,
                              void* d_out, int out_size, void* d_ws, size_t ws_size,
                              hipStream_t stream) {
  const float* x   = (const float*)d_in[0];
  const float* Wuw = (const float*)d_in[1];
  const float* Wub = (const float*)d_in[2];
  const float* Whw = (const float*)d_in[3];
  const float* Whb = (const float*)d_in[4];
  // d_in[5] (fft_H) intentionally UNUSED: recomputed on-device in fp64.
  float* out = (float*)d_out;
  float* ws  = (float*)d_ws;

  float* fftu = ws + FFTU_OFF;
  float* uz   = ws + UZ_OFF;       // f64 scratch -> ubuf -> Z o-chunks
  float* fHd  = ws + FHD_OFF;
  float2* tw  = (float2*)(ws + TW_OFF);
  float* Hbuf = ws + HBUF_OFF;
  double* D   = (double*)uz;

  k0_tw<<<8, 256, 0, stream>>>(tw);
  kA_expm<<<1, 256, 0, stream>>>(D);
  kB_cols<<<32, 256, 0, stream>>>(D, Hbuf);
  kC_fft<<<NMEM, 256, 0, stream>>>(Hbuf, tw, fHd);
  k1t<<<dim3(NSEQ / 128, NOUTCH / 64, NB), 256, 0, stream>>>(x, Wuw, Wub, Whb, out, uz);
  k2f<<<NB * NFEAT, 256, 0, stream>>>(uz, tw, fftu);
  for (int oc = 0; oc < NOCH; ++oc) {
    int ob0 = oc * OCH;
    k3o<<<dim3(OCH / 2, (KBINS + 63) / 64), 256, 0, stream>>>(Whw, fHd, fftu, uz, ob0);
    k4f<<<NB * OCH, 256, 0, stream>>>(uz, tw, out, ob0);
  }
}